// Round 2
// baseline (2556.406 us; speedup 1.0000x reference)
//
#include <hip/hip_runtime.h>
#include <stdint.h>

// RITS-I: precompute (GEMMs over B*T) + barrier-free 1-wave-per-batch recurrence.
// B=256, T=2048, I=64, H=32.

#define LOG2E 1.4426950408889634f

__device__ __forceinline__ float rdlane(float v, int l) {
  return __int_as_float(__builtin_amdgcn_readlane(__float_as_int(v), l));
}
__device__ __forceinline__ uint16_t f2bf(float f) {
  uint32_t u = __float_as_uint(f);
  u = u + 0x7FFFu + ((u >> 16) & 1u);
  return (uint16_t)(u >> 16);
}

// ---------------- G1: preg[b,t,128] = W_ih_xc*(m*x) + W_ih_m*m + b_ih + b_hh (bf16, pair-permuted) ----------
// A = [m*x (k<64), m (k>=64)] [BT,128]; W1[k][g] = W_ih[g][k]. Tile 128 rows x 128 cols, K in 2 chunks of 64.
__global__ __launch_bounds__(256, 2) void g1_preg(
    const float* __restrict__ values, const float* __restrict__ masks,
    const float* __restrict__ W_ih, const float* __restrict__ b_ih,
    const float* __restrict__ b_hh, uint16_t* __restrict__ pregP,
    int t0, int ns)
{
  __shared__ __align__(16) unsigned char smem[67584 + 512];
  float* AT = (float*)smem;                 // [64][132]  AT[k][r]
  float* WT = (float*)(smem + 33792);       // [64][132]  WT[k][g]
  uint16_t* OT = (uint16_t*)smem;           // [128][128] reuse for epilogue

  const int tid = threadIdx.x;
  const int row0 = blockIdx.x * 128;
  const int b  = row0 / ns;
  const int s0 = row0 - b * ns;
  const size_t inbase = ((size_t)b * 2048 + t0 + s0) * 64;

  const int rt = tid & 15, ct = tid >> 4;
  const int r0 = rt * 8, c0 = ct * 8;

  float acc[8][8];
  #pragma unroll
  for (int i = 0; i < 8; ++i)
    #pragma unroll
    for (int j = 0; j < 8; ++j) acc[i][j] = 0.f;

  float4 mr[8];

  for (int kc = 0; kc < 2; ++kc) {
    // ---- stage A chunk (transposed) and W chunk ----
    #pragma unroll
    for (int i = 0; i < 8; ++i) {
      int idx = tid + 256 * i;
      int row = idx >> 4, c4 = idx & 15;
      if (kc == 0) {
        float4 xv = *(const float4*)(values + inbase + (size_t)row * 64 + c4 * 4);
        float4 mv = *(const float4*)(masks  + inbase + (size_t)row * 64 + c4 * 4);
        mr[i] = mv;
        AT[(c4*4+0)*132 + row] = xv.x * mv.x;
        AT[(c4*4+1)*132 + row] = xv.y * mv.y;
        AT[(c4*4+2)*132 + row] = xv.z * mv.z;
        AT[(c4*4+3)*132 + row] = xv.w * mv.w;
      } else {
        float4 mv = mr[i];
        AT[(c4*4+0)*132 + row] = mv.x;
        AT[(c4*4+1)*132 + row] = mv.y;
        AT[(c4*4+2)*132 + row] = mv.z;
        AT[(c4*4+3)*132 + row] = mv.w;
      }
      // W: rows = gates (128), cols = k-slice
      float4 wv = *(const float4*)(W_ih + (size_t)row * 128 + kc * 64 + c4 * 4);
      WT[(c4*4+0)*132 + row] = wv.x;
      WT[(c4*4+1)*132 + row] = wv.y;
      WT[(c4*4+2)*132 + row] = wv.z;
      WT[(c4*4+3)*132 + row] = wv.w;
    }
    __syncthreads();
    #pragma unroll 2
    for (int k = 0; k < 64; ++k) {
      float4 a0 = *(const float4*)(AT + k*132 + r0);
      float4 a1 = *(const float4*)(AT + k*132 + r0 + 4);
      float4 w0 = *(const float4*)(WT + k*132 + c0);
      float4 w1 = *(const float4*)(WT + k*132 + c0 + 4);
      float av[8] = {a0.x,a0.y,a0.z,a0.w,a1.x,a1.y,a1.z,a1.w};
      float wv[8] = {w0.x,w0.y,w0.z,w0.w,w1.x,w1.y,w1.z,w1.w};
      #pragma unroll
      for (int i = 0; i < 8; ++i)
        #pragma unroll
        for (int j = 0; j < 8; ++j) acc[i][j] = fmaf(av[i], wv[j], acc[i][j]);
    }
    __syncthreads();
  }

  // ---- epilogue: +bias, bf16, pair-permute (gate g -> pos 2*(g&63)+(g>>6)), linear store ----
  float bias[8];
  #pragma unroll
  for (int j = 0; j < 8; ++j) bias[j] = b_ih[c0+j] + b_hh[c0+j];
  #pragma unroll
  for (int i = 0; i < 8; ++i)
    #pragma unroll
    for (int j = 0; j < 8; ++j) {
      int g = c0 + j;
      int pos = ((g & 63) << 1) + (g >> 6);
      OT[(r0 + i) * 128 + pos] = f2bf(acc[i][j] + bias[j]);
    }
  __syncthreads();
  const char* src = (const char*)smem + tid * 128;
  char* dst = (char*)pregP + (size_t)row0 * 256 + tid * 128;
  #pragma unroll
  for (int i = 0; i < 8; ++i)
    *(float4*)(dst + i*16) = *(const float4*)(src + i*16);
}

// ---------------- G2: gamma[b,t,32] = exp(-relu(W_decay*d + b_decay)) bf16 ----------------
__global__ __launch_bounds__(256, 2) void g2_gamma(
    const float* __restrict__ deltas, const float* __restrict__ W_decay,
    const float* __restrict__ b_decay, uint16_t* __restrict__ gammaP,
    int t0, int ns)
{
  __shared__ __align__(16) unsigned char smem[33792 + 8704];
  float* AT = (float*)smem;                 // [64][132]  AT[k][r]
  float* WD = (float*)(smem + 33792);       // [64][34]   WD[k][c]
  uint16_t* OT = (uint16_t*)smem;           // [128][32] reuse

  const int tid = threadIdx.x;
  const int row0 = blockIdx.x * 128;
  const int b  = row0 / ns;
  const int s0 = row0 - b * ns;
  const size_t inbase = ((size_t)b * 2048 + t0 + s0) * 64;

  #pragma unroll
  for (int i = 0; i < 8; ++i) {
    int idx = tid + 256 * i;
    int row = idx >> 4, c4 = idx & 15;
    float4 dv = *(const float4*)(deltas + inbase + (size_t)row * 64 + c4 * 4);
    AT[(c4*4+0)*132 + row] = dv.x;
    AT[(c4*4+1)*132 + row] = dv.y;
    AT[(c4*4+2)*132 + row] = dv.z;
    AT[(c4*4+3)*132 + row] = dv.w;
  }
  #pragma unroll
  for (int i = 0; i < 2; ++i) {
    int idx = tid + 256 * i;
    int j = idx >> 4, c4 = idx & 15;
    float4 wv = *(const float4*)(W_decay + (size_t)j * 64 + c4 * 4);
    WD[(c4*4+0)*34 + j] = wv.x;
    WD[(c4*4+1)*34 + j] = wv.y;
    WD[(c4*4+2)*34 + j] = wv.z;
    WD[(c4*4+3)*34 + j] = wv.w;
  }
  __syncthreads();

  const int rt = tid & 15, ct = tid >> 4;
  const int r0 = rt * 8, c0 = ct * 2;
  float acc[8][2];
  #pragma unroll
  for (int i = 0; i < 8; ++i) { acc[i][0] = 0.f; acc[i][1] = 0.f; }

  #pragma unroll 2
  for (int k = 0; k < 64; ++k) {
    float4 a0 = *(const float4*)(AT + k*132 + r0);
    float4 a1 = *(const float4*)(AT + k*132 + r0 + 4);
    float2 w  = *(const float2*)(WD + k*34 + c0);
    float av[8] = {a0.x,a0.y,a0.z,a0.w,a1.x,a1.y,a1.z,a1.w};
    #pragma unroll
    for (int i = 0; i < 8; ++i) {
      acc[i][0] = fmaf(av[i], w.x, acc[i][0]);
      acc[i][1] = fmaf(av[i], w.y, acc[i][1]);
    }
  }
  __syncthreads();
  float bd0 = b_decay[c0], bd1 = b_decay[c0+1];
  #pragma unroll
  for (int i = 0; i < 8; ++i) {
    float z0 = fmaxf(acc[i][0] + bd0, 0.f);
    float z1 = fmaxf(acc[i][1] + bd1, 0.f);
    OT[(r0+i)*32 + c0]   = f2bf(__builtin_amdgcn_exp2f(-z0 * LOG2E));
    OT[(r0+i)*32 + c0+1] = f2bf(__builtin_amdgcn_exp2f(-z1 * LOG2E));
  }
  __syncthreads();
  const char* src = (const char*)smem + tid * 32;
  char* dst = (char*)gammaP + (size_t)row0 * 64 + tid * 32;
  *(float4*)(dst)      = *(const float4*)(src);
  *(float4*)(dst + 16) = *(const float4*)(src + 16);
}

// ---------------- OMB: pack (m>0.5) bits, 64 per step ----------------
__global__ __launch_bounds__(64) void omb_kernel(
    const float* __restrict__ masks, unsigned long long* __restrict__ omP,
    int t0, int ns)
{
  const int l = threadIdx.x;
  const int r0 = blockIdx.x * 64;
  const int b  = r0 / ns;
  const int s0 = r0 - b * ns;
  const float* mp = masks + ((size_t)b * 2048 + t0 + s0) * 64 + l;
  #pragma unroll 1
  for (int s = 0; s < 64; ++s) {
    float m = mp[(size_t)s * 64];
    unsigned long long bits = __ballot(m > 0.5f);
    if (l == 0) omP[r0 + s] = bits;
  }
}

// ---------------- P2: barrier-free recurrence, 1 wave per batch row ----------------
#define CB 4672   // chunk bytes: x 2048 | preg 2048 | gamma 512 | om 64

__global__ __launch_bounds__(64, 1) void p2_rnn(
    const float* __restrict__ values, const uint16_t* __restrict__ gammaP,
    const uint16_t* __restrict__ pregP, const unsigned long long* __restrict__ omP,
    const float* __restrict__ W_ih, const float* __restrict__ W_hh,
    const float* __restrict__ W_reg, const float* __restrict__ b_reg,
    const float* __restrict__ W_out, const float* __restrict__ b_out,
    float* __restrict__ hc, float* __restrict__ y, float* __restrict__ imp,
    int t0, int ns)
{
  const int l = threadIdx.x;
  const int b = blockIdx.x;
  __shared__ __align__(16) unsigned char sb[2 * CB + 16];

  // ---- weights to registers (static arrays, fully unrolled use) ----
  float whh0[32], whh1[32], wreg[32], wxc0[64], wxc1[64];
  {
    const float4* p;
    p = (const float4*)(W_hh + (size_t)l * 32);
    #pragma unroll
    for (int i = 0; i < 8; ++i) { float4 v = p[i]; whh0[4*i]=v.x; whh0[4*i+1]=v.y; whh0[4*i+2]=v.z; whh0[4*i+3]=v.w; }
    p = (const float4*)(W_hh + (size_t)(64 + l) * 32);
    #pragma unroll
    for (int i = 0; i < 8; ++i) { float4 v = p[i]; whh1[4*i]=v.x; whh1[4*i+1]=v.y; whh1[4*i+2]=v.z; whh1[4*i+3]=v.w; }
    p = (const float4*)(W_reg + (size_t)l * 32);
    #pragma unroll
    for (int i = 0; i < 8; ++i) { float4 v = p[i]; wreg[4*i]=v.x; wreg[4*i+1]=v.y; wreg[4*i+2]=v.z; wreg[4*i+3]=v.w; }
    p = (const float4*)(W_ih + (size_t)l * 128);
    #pragma unroll
    for (int i = 0; i < 16; ++i) { float4 v = p[i]; wxc0[4*i]=v.x; wxc0[4*i+1]=v.y; wxc0[4*i+2]=v.z; wxc0[4*i+3]=v.w; }
    p = (const float4*)(W_ih + (size_t)(64 + l) * 128);
    #pragma unroll
    for (int i = 0; i < 16; ++i) { float4 v = p[i]; wxc1[4*i]=v.x; wxc1[4*i+1]=v.y; wxc1[4*i+2]=v.z; wxc1[4*i+3]=v.w; }
  }
  const float bregl = b_reg[l];
  const float A1 = (l < 32) ? (-2.f * LOG2E) : (-LOG2E);
  const float B1 = (l < 32) ? 2.f : 1.f;
  const float C1 = (l < 32) ? -1.f : 0.f;

  float h, c;
  if (t0 == 0) { h = 0.f; c = 0.f; }
  else { h = hc[b*32 + (l & 31)]; c = hc[8192 + b*32 + (l & 31)]; }

  // ---- stream prefetch setup: 5 b128 loads/chunk/lane ----
  const char* p0 = (const char*)(values + ((size_t)b * 2048 + t0) * 64) + l * 16;
  const char* p1 = p0 + 1024;
  const char* p2 = (const char*)(pregP + (size_t)b * ns * 128) + l * 16;
  const char* p3 = p2 + 1024;
  const char* p4; int str4, dst4;
  if (l < 32)      { p4 = (const char*)(gammaP + (size_t)b * ns * 32) + l * 16;       str4 = 512; dst4 = 4096 + l * 16; }
  else if (l < 36) { p4 = (const char*)(omP + (size_t)b * ns) + (l - 32) * 16;        str4 = 64;  dst4 = 4608 + (l - 32) * 16; }
  else             { p4 = (const char*)(gammaP + (size_t)b * ns * 32);                str4 = 0;   dst4 = -1; }

  float4 r0v = *(const float4*)p0;
  float4 r1v = *(const float4*)p1;
  float4 r2v = *(const float4*)p2;
  float4 r3v = *(const float4*)p3;
  float4 r4v = *(const float4*)p4;

  float* impp = imp + ((size_t)b * 2048 + t0) * 64 + l;
  const int nch = ns / 8;

  #pragma unroll 1
  for (int ch = 0; ch < nch; ++ch) {
    unsigned char* buf = sb + (ch & 1) * CB;
    *(float4*)(buf + l * 16)        = r0v;
    *(float4*)(buf + 1024 + l * 16) = r1v;
    *(float4*)(buf + 2048 + l * 16) = r2v;
    *(float4*)(buf + 3072 + l * 16) = r3v;
    *(float4*)((dst4 >= 0) ? (buf + dst4) : (sb + 2 * CB)) = r4v;
    if (ch + 1 < nch) {
      p0 += 2048; p1 += 2048; p2 += 2048; p3 += 2048; p4 += str4;
      r0v = *(const float4*)p0;
      r1v = *(const float4*)p1;
      r2v = *(const float4*)p2;
      r3v = *(const float4*)p3;
      r4v = *(const float4*)p4;
    }
    asm volatile("s_waitcnt lgkmcnt(0)" ::: "memory");

    const float* xs        = (const float*)buf;
    const uint16_t* pgs    = (const uint16_t*)(buf + 2048);
    const uint16_t* gms    = (const uint16_t*)(buf + 4096);
    const unsigned long long* oms = (const unsigned long long*)(buf + 4608);

    #pragma unroll 1
    for (int s = 0; s < 8; ++s) {
      uint32_t pg = ((const uint32_t*)(pgs + s * 128))[l];
      float a0 = __uint_as_float(pg << 16);
      float a1 = __uint_as_float(pg & 0xFFFF0000u);
      float gm = __uint_as_float(((uint32_t)gms[s * 32 + (l & 31)]) << 16);
      unsigned long long ob = oms[s];
      uint32_t ow = (l < 32) ? (uint32_t)ob : (uint32_t)(ob >> 32);
      uint32_t mbit = (ow >> (l & 31)) & 1u;
      float x = xs[s * 64 + l];

      float hd = h * gm;
      float u = 0.f;
      #pragma unroll
      for (int k = 0; k < 32; ++k) {
        float bc = rdlane(hd, k);
        a0 = fmaf(bc, whh0[k], a0);
        a1 = fmaf(bc, whh1[k], a1);
        u  = fmaf(bc, wreg[k], u);
      }
      float ub = u + bregl;
      float xc = mbit ? x : ub;
      float v  = mbit ? 0.f : ub;
      impp[(size_t)(ch * 8 + s) * 64] = xc;
      #pragma unroll
      for (int k = 0; k < 64; ++k) {
        float bc = rdlane(v, k);
        a0 = fmaf(bc, wxc0[k], a0);
        a1 = fmaf(bc, wxc1[k], a1);
      }
      // pointwise: lane<32 holds (i,g); lane>=32 holds (f,o); h,c live on lanes<32
      float e0 = __builtin_amdgcn_exp2f(a0 * (-LOG2E));
      float r0s = __builtin_amdgcn_rcpf(1.f + e0);            // sigmoid(a0)
      float e1 = __builtin_amdgcn_exp2f(a1 * A1);
      float r1s = fmaf(B1, __builtin_amdgcn_rcpf(1.f + e1), C1); // tanh or sigmoid
      float sfx = __shfl_xor(r0s, 32);
      float sox = __shfl_xor(r1s, 32);
      float cn = fmaf(sfx, c, r0s * r1s);
      float e2 = __builtin_amdgcn_exp2f(cn * (-2.f * LOG2E));
      float tc = fmaf(2.f, __builtin_amdgcn_rcpf(1.f + e2), -1.f);
      c = cn;
      h = sox * tc;
    }
  }

  if (l < 32) { hc[b*32 + l] = h; hc[8192 + b*32 + l] = c; }

  if (t0 + ns == 2048) {
    float wo0 = (l < 32) ? W_out[l] : 0.f;
    float wo1 = (l < 32) ? W_out[32 + l] : 0.f;
    float t0s = (l < 32) ? h * wo0 : 0.f;
    float t1s = (l < 32) ? h * wo1 : 0.f;
    #pragma unroll
    for (int m = 16; m >= 1; m >>= 1) {
      t0s += __shfl_xor(t0s, m);
      t1s += __shfl_xor(t1s, m);
    }
    if (l == 0) {
      y[b*2]     = t0s + b_out[0];
      y[b*2 + 1] = t1s + b_out[1];
    }
  }
}

extern "C" void kernel_launch(void* const* d_in, const int* in_sizes, int n_in,
                              void* d_out, int out_size, void* d_ws, size_t ws_size,
                              hipStream_t stream) {
  const float* values  = (const float*)d_in[0];
  const float* masks   = (const float*)d_in[1];
  const float* deltas  = (const float*)d_in[2];
  const float* W_decay = (const float*)d_in[3];
  const float* b_decay = (const float*)d_in[4];
  const float* W_reg   = (const float*)d_in[5];
  const float* b_reg   = (const float*)d_in[6];
  const float* W_ih    = (const float*)d_in[7];
  const float* b_ih    = (const float*)d_in[8];
  const float* W_hh    = (const float*)d_in[9];
  const float* b_hh    = (const float*)d_in[10];
  const float* W_out   = (const float*)d_in[11];
  const float* b_out   = (const float*)d_in[12];
  float* y   = (float*)d_out;
  float* imp = (float*)d_out + 512;

  // ws layout: hc [64KB] | gamma bf16 [256*SEG*32] | preg bf16 [256*SEG*128] | ombits [256*SEG*8B]
  float* hc = (float*)d_ws;
  const size_t perStep = 256ull * (32*2 + 128*2 + 8);   // 83968 B per seg-step
  int SEG = 2048;
  size_t avail = ws_size > 65536 ? ws_size - 65536 : 0;
  size_t maxSteps = avail / perStep;
  if (maxSteps < 2048) SEG = (int)(maxSteps / 128 * 128);
  if (SEG < 128) SEG = 128;
  uint16_t* gammaP = (uint16_t*)((char*)d_ws + 65536);
  uint16_t* pregP  = gammaP + (size_t)256 * SEG * 32;
  unsigned long long* omP = (unsigned long long*)(pregP + (size_t)256 * SEG * 128);

  for (int t0 = 0; t0 < 2048; t0 += SEG) {
    int ns = 2048 - t0; if (ns > SEG) ns = SEG;
    hipLaunchKernelGGL(g1_preg,  dim3(2 * ns), dim3(256), 0, stream,
                       values, masks, W_ih, b_ih, b_hh, pregP, t0, ns);
    hipLaunchKernelGGL(g2_gamma, dim3(2 * ns), dim3(256), 0, stream,
                       deltas, W_decay, b_decay, gammaP, t0, ns);
    hipLaunchKernelGGL(omb_kernel, dim3(4 * ns), dim3(64), 0, stream,
                       masks, omP, t0, ns);
    hipLaunchKernelGGL(p2_rnn, dim3(256), dim3(64), 0, stream,
                       values, gammaP, pregP, omP, W_ih, W_hh, W_reg, b_reg,
                       W_out, b_out, hc, y, imp, t0, ns);
  }
}

// Round 3
// 2475.773 us; speedup vs baseline: 1.0326x; 1.0326x over previous
//
#include <hip/hip_runtime.h>
#include <stdint.h>

#define L2E 1.4426950408889634f

typedef __attribute__((ext_vector_type(8))) short short8;
typedef __attribute__((ext_vector_type(4))) float floatx4;

__device__ __forceinline__ uint32_t pkbf(float lo, float hi) {
  uint32_t r;
  asm("v_cvt_pk_bf16_f32 %0, %1, %2" : "=v"(r) : "v"(lo), "v"(hi));
  return r;
}

// ================= G1: preg/mx/m1 streams =================
// preg[g] = W_ih[:, :64]*(m*x) + W_ih[:, 64:]*m + b_ih + b_hh  (f32, slot layout)
// mx = m*x, m1 = 1-m  (f32, u-slot layout)
__global__ __launch_bounds__(256, 2) void g1_preg(
    const float* __restrict__ values, const float* __restrict__ masks,
    const float* __restrict__ W_ih, const float* __restrict__ b_ih,
    const float* __restrict__ b_hh, float* __restrict__ pregS,
    float* __restrict__ mxS, float* __restrict__ m1S, int t0, int ns)
{
  __shared__ __align__(16) float AT[64*132];
  __shared__ __align__(16) float WT[64*132];
  const int tid = threadIdx.x;
  const int tblk = blockIdx.x, gr = blockIdx.y;
  const int tbase = t0 + tblk*8;
  const int rt = tid & 15, ct = tid >> 4;
  const int r0 = rt*8, c0g = ct*8;

  float acc[8][8];
  #pragma unroll
  for (int i = 0; i < 8; ++i)
    #pragma unroll
    for (int j = 0; j < 8; ++j) acc[i][j] = 0.f;
  float4 mr[8];

  for (int kc = 0; kc < 2; ++kc) {
    #pragma unroll
    for (int i = 0; i < 8; ++i) {
      int idx = tid + 256*i;
      int lr = idx >> 4, c4 = idx & 15;
      int bl = lr >> 3, ts = lr & 7;
      if (kc == 0) {
        size_t inoff = ((size_t)(gr*16 + bl)*2048 + tbase + ts)*64 + c4*4;
        float4 xv = *(const float4*)(values + inoff);
        float4 mv = *(const float4*)(masks + inoff);
        mr[i] = mv;
        float4 mx4 = make_float4(xv.x*mv.x, xv.y*mv.y, xv.z*mv.z, xv.w*mv.w);
        AT[(c4*4+0)*132 + lr] = mx4.x;
        AT[(c4*4+1)*132 + lr] = mx4.y;
        AT[(c4*4+2)*132 + lr] = mx4.z;
        AT[(c4*4+3)*132 + lr] = mx4.w;
        size_t rb = ((size_t)gr*ns + tblk*8 + ts)*1024 + (size_t)(c4>>2)*256
                  + (size_t)(16*(c4&3) + bl)*4;
        *(float4*)(mxS + rb) = mx4;
        *(float4*)(m1S + rb) = make_float4(1.f-mv.x, 1.f-mv.y, 1.f-mv.z, 1.f-mv.w);
      } else {
        float4 mv = mr[i];
        AT[(c4*4+0)*132 + lr] = mv.x;
        AT[(c4*4+1)*132 + lr] = mv.y;
        AT[(c4*4+2)*132 + lr] = mv.z;
        AT[(c4*4+3)*132 + lr] = mv.w;
      }
      float4 wv = *(const float4*)(W_ih + (size_t)lr*128 + kc*64 + c4*4);
      WT[(c4*4+0)*132 + lr] = wv.x;
      WT[(c4*4+1)*132 + lr] = wv.y;
      WT[(c4*4+2)*132 + lr] = wv.z;
      WT[(c4*4+3)*132 + lr] = wv.w;
    }
    __syncthreads();
    #pragma unroll 2
    for (int k = 0; k < 64; ++k) {
      float4 a0 = *(const float4*)(AT + k*132 + r0);
      float4 a1 = *(const float4*)(AT + k*132 + r0 + 4);
      float4 w0 = *(const float4*)(WT + k*132 + c0g);
      float4 w1 = *(const float4*)(WT + k*132 + c0g + 4);
      float av[8] = {a0.x,a0.y,a0.z,a0.w,a1.x,a1.y,a1.z,a1.w};
      float wv[8] = {w0.x,w0.y,w0.z,w0.w,w1.x,w1.y,w1.z,w1.w};
      #pragma unroll
      for (int i = 0; i < 8; ++i)
        #pragma unroll
        for (int j = 0; j < 8; ++j) acc[i][j] = fmaf(av[i], wv[j], acc[i][j]);
    }
    __syncthreads();
  }

  float bias[8];
  #pragma unroll
  for (int j = 0; j < 8; ++j) bias[j] = b_ih[c0g+j] + b_hh[c0g+j];
  const int bl = rt;   // rows r0..r0+7 share b_loc = rt, ts = i
  #pragma unroll
  for (int i = 0; i < 8; ++i) {
    size_t rec = (size_t)gr*ns + tblk*8 + i;
    #pragma unroll
    for (int jq = 0; jq < 2; ++jq) {
      int g0 = c0g + 4*jq;
      size_t off = rec*2048 + (size_t)(g0>>4)*256 + (size_t)(16*((g0&15)>>2) + bl)*4;
      *(float4*)(pregS + off) = make_float4(
          acc[i][4*jq+0]+bias[4*jq+0], acc[i][4*jq+1]+bias[4*jq+1],
          acc[i][4*jq+2]+bias[4*jq+2], acc[i][4*jq+3]+bias[4*jq+3]);
    }
  }
}

// ================= G2: gamma stream (f32, h-slot layout) =================
__global__ __launch_bounds__(256, 2) void g2_gamma(
    const float* __restrict__ deltas, const float* __restrict__ W_decay,
    const float* __restrict__ b_decay, float* __restrict__ gamS, int t0, int ns)
{
  __shared__ __align__(16) float AT[64*132];
  __shared__ __align__(16) float WD[64*34];
  const int tid = threadIdx.x;
  const int tblk = blockIdx.x, gr = blockIdx.y;
  const int tbase = t0 + tblk*8;

  #pragma unroll
  for (int i = 0; i < 8; ++i) {
    int idx = tid + 256*i;
    int lr = idx >> 4, c4 = idx & 15;
    int bl = lr >> 3, ts = lr & 7;
    size_t inoff = ((size_t)(gr*16 + bl)*2048 + tbase + ts)*64 + c4*4;
    float4 dv = *(const float4*)(deltas + inoff);
    AT[(c4*4+0)*132 + lr] = dv.x;
    AT[(c4*4+1)*132 + lr] = dv.y;
    AT[(c4*4+2)*132 + lr] = dv.z;
    AT[(c4*4+3)*132 + lr] = dv.w;
  }
  #pragma unroll
  for (int i = 0; i < 2; ++i) {
    int idx = tid + 256*i;
    int j = idx >> 4, c4 = idx & 15;
    float4 wv = *(const float4*)(W_decay + (size_t)j*64 + c4*4);
    WD[(c4*4+0)*34 + j] = wv.x;
    WD[(c4*4+1)*34 + j] = wv.y;
    WD[(c4*4+2)*34 + j] = wv.z;
    WD[(c4*4+3)*34 + j] = wv.w;
  }
  __syncthreads();

  const int rt = tid & 15, ct = tid >> 4;
  const int r0 = rt*8, c0 = ct*2;
  float acc[8][2];
  #pragma unroll
  for (int i = 0; i < 8; ++i) { acc[i][0] = 0.f; acc[i][1] = 0.f; }

  #pragma unroll 2
  for (int k = 0; k < 64; ++k) {
    float4 a0 = *(const float4*)(AT + k*132 + r0);
    float4 a1 = *(const float4*)(AT + k*132 + r0 + 4);
    float w0 = WD[k*34 + c0], w1 = WD[k*34 + c0 + 1];
    float av[8] = {a0.x,a0.y,a0.z,a0.w,a1.x,a1.y,a1.z,a1.w};
    #pragma unroll
    for (int i = 0; i < 8; ++i) {
      acc[i][0] = fmaf(av[i], w0, acc[i][0]);
      acc[i][1] = fmaf(av[i], w1, acc[i][1]);
    }
  }
  const float bd0 = b_decay[c0], bd1 = b_decay[c0+1];
  const int bl = rt;
  #pragma unroll
  for (int i = 0; i < 8; ++i) {
    size_t rec = (size_t)gr*ns + tblk*8 + i;
    #pragma unroll
    for (int jx = 0; jx < 2; ++jx) {
      int j = c0 + jx;
      float z = fmaxf(acc[i][jx] + (jx ? bd1 : bd0), 0.f);
      float gv = __builtin_amdgcn_exp2f(-z * L2E);
      gamS[rec*512 + (size_t)(j>>4)*256 + (size_t)(16*((j&15)>>2) + bl)*4 + (j&3)] = gv;
    }
  }
}

// ================= P3: MFMA recurrence, 1 wave = 16 batch rows =================
#define PW(GI, GF, GG, GO, CC, HH) do { \
  float _si = __builtin_amdgcn_rcpf(1.f + __builtin_amdgcn_exp2f((GI) * -L2E)); \
  float _sf = __builtin_amdgcn_rcpf(1.f + __builtin_amdgcn_exp2f((GF) * -L2E)); \
  float _so = __builtin_amdgcn_rcpf(1.f + __builtin_amdgcn_exp2f((GO) * -L2E)); \
  float _tg = 1.f - 2.f*__builtin_amdgcn_rcpf(1.f + __builtin_amdgcn_exp2f((GG) * (2.f*L2E))); \
  float _cn = fmaf(_sf, (CC), _si*_tg); \
  float _tc = 1.f - 2.f*__builtin_amdgcn_rcpf(1.f + __builtin_amdgcn_exp2f(_cn * (2.f*L2E))); \
  (CC) = _cn; (HH) = _so * _tc; \
} while (0)

#define PF(N) do { \
  _Pragma("unroll") for (int q = 0; q < 8; ++q) PR##N[q] = pPreg[q*64]; \
  GM##N[0] = pGam[0]; GM##N[1] = pGam[64]; \
  _Pragma("unroll") for (int q = 0; q < 4; ++q) { MX##N[q] = pMx[q*64]; M1##N[q] = pM1[q*64]; } \
  pPreg += 512; pGam += 128; pMx += 256; pM1 += 256; \
} while (0)

#define STEP(S, N) do { \
  PF(N); \
  float4 hd0 = make_float4(h0.x*GM##S[0].x, h0.y*GM##S[0].y, h0.z*GM##S[0].z, h0.w*GM##S[0].w); \
  float4 hd1 = make_float4(h1.x*GM##S[1].x, h1.y*GM##S[1].y, h1.z*GM##S[1].z, h1.w*GM##S[1].w); \
  *(uint2*)(hdB + b*80 + w*8)      = make_uint2(pkbf(hd0.x,hd0.y), pkbf(hd0.z,hd0.w)); \
  *(uint2*)(hdB + b*80 + 32 + w*8) = make_uint2(pkbf(hd1.x,hd1.y), pkbf(hd1.z,hd1.w)); \
  asm volatile("s_waitcnt lgkmcnt(0)" ::: "memory"); \
  short8 Bhd = *(short8*)(hdB + b*80 + w*16); \
  floatx4 uu[4]; floatx4 ga[8]; \
  _Pragma("unroll") for (int t = 0; t < 4; ++t) \
    uu[t] = __builtin_amdgcn_mfma_f32_16x16x32_bf16(WregA[t], Bhd, brC[t], 0, 0, 0); \
  _Pragma("unroll") for (int t = 0; t < 8; ++t) { \
    floatx4 ci = {PR##S[t].x, PR##S[t].y, PR##S[t].z, PR##S[t].w}; \
    ga[t] = __builtin_amdgcn_mfma_f32_16x16x32_bf16(WhhA[t], Bhd, ci, 0, 0, 0); \
  } \
  _Pragma("unroll") for (int t = 0; t < 4; ++t) { \
    float v0 = M1##S[t].x * uu[t][0], v1 = M1##S[t].y * uu[t][1]; \
    float v2 = M1##S[t].z * uu[t][2], v3 = M1##S[t].w * uu[t][3]; \
    *(float4*)(impP + t*16) = make_float4(v0 + MX##S[t].x, v1 + MX##S[t].y, \
                                          v2 + MX##S[t].z, v3 + MX##S[t].w); \
    *(uint2*)(vB + b*144 + t*32 + w*8) = make_uint2(pkbf(v0,v1), pkbf(v2,v3)); \
  } \
  asm volatile("s_waitcnt lgkmcnt(0)" ::: "memory"); \
  short8 Bv0 = *(short8*)(vB + b*144 + w*16); \
  short8 Bv1 = *(short8*)(vB + b*144 + 64 + w*16); \
  _Pragma("unroll") for (int t = 0; t < 8; ++t) { \
    ga[t] = __builtin_amdgcn_mfma_f32_16x16x32_bf16(WxcA0[t], Bv0, ga[t], 0, 0, 0); \
    ga[t] = __builtin_amdgcn_mfma_f32_16x16x32_bf16(WxcA1[t], Bv1, ga[t], 0, 0, 0); \
  } \
  impP += 64; \
  PW(ga[0][0], ga[2][0], ga[4][0], ga[6][0], cv0.x, h0.x); \
  PW(ga[0][1], ga[2][1], ga[4][1], ga[6][1], cv0.y, h0.y); \
  PW(ga[0][2], ga[2][2], ga[4][2], ga[6][2], cv0.z, h0.z); \
  PW(ga[0][3], ga[2][3], ga[4][3], ga[6][3], cv0.w, h0.w); \
  PW(ga[1][0], ga[3][0], ga[5][0], ga[7][0], cv1.x, h1.x); \
  PW(ga[1][1], ga[3][1], ga[5][1], ga[7][1], cv1.y, h1.y); \
  PW(ga[1][2], ga[3][2], ga[5][2], ga[7][2], cv1.z, h1.z); \
  PW(ga[1][3], ga[3][3], ga[5][3], ga[7][3], cv1.w, h1.w); \
} while (0)

__global__ __launch_bounds__(64, 1) void p3_rnn(
    const float* __restrict__ W_hh, const float* __restrict__ W_reg,
    const float* __restrict__ W_ih, const float* __restrict__ b_reg,
    const float* __restrict__ W_out, const float* __restrict__ b_out,
    const float* __restrict__ pregS, const float* __restrict__ gamS,
    const float* __restrict__ mxS, const float* __restrict__ m1S,
    float* __restrict__ hc, float* __restrict__ y, float* __restrict__ imp,
    int t0, int ns)
{
  const int l = threadIdx.x, gr = blockIdx.x;
  const int b = l & 15, w = l >> 4;
  __shared__ __align__(16) char hdB[16*80];
  __shared__ __align__(16) char vB[16*144];

  auto mkfrag = [&](const float* p) -> short8 {
    float4 a = *(const float4*)p;
    float4 c = *(const float4*)(p + 4);
    union { uint32_t u[4]; short8 s; } z;
    z.u[0] = pkbf(a.x, a.y); z.u[1] = pkbf(a.z, a.w);
    z.u[2] = pkbf(c.x, c.y); z.u[3] = pkbf(c.z, c.w);
    return z.s;
  };

  // weights as A-fragments: lane holds row m = (16t + b), k = 8w..8w+7
  short8 WhhA[8], WxcA0[8], WxcA1[8], WregA[4];
  #pragma unroll
  for (int t = 0; t < 8; ++t) {
    WhhA[t]  = mkfrag(W_hh + (size_t)(16*t + b)*32 + 8*w);
    WxcA0[t] = mkfrag(W_ih + (size_t)(16*t + b)*128 + 8*w);
    WxcA1[t] = mkfrag(W_ih + (size_t)(16*t + b)*128 + 32 + 8*w);
  }
  #pragma unroll
  for (int t = 0; t < 4; ++t) WregA[t] = mkfrag(W_reg + (size_t)(16*t + b)*32 + 8*w);

  floatx4 brC[4];
  #pragma unroll
  for (int t = 0; t < 4; ++t) {
    float4 v = *(const float4*)(b_reg + 16*t + 4*w);
    brC[t] = (floatx4){v.x, v.y, v.z, v.w};
  }

  float4 h0, h1, cv0, cv1;
  if (t0 == 0) {
    h0 = h1 = cv0 = cv1 = make_float4(0.f, 0.f, 0.f, 0.f);
  } else {
    const float* hp = hc + ((size_t)gr*64 + l)*16;
    h0  = *(const float4*)(hp);
    h1  = *(const float4*)(hp + 4);
    cv0 = *(const float4*)(hp + 8);
    cv1 = *(const float4*)(hp + 12);
  }

  const float4* pPreg = (const float4*)pregS + (size_t)gr*ns*512 + l;
  const float4* pGam  = (const float4*)gamS  + (size_t)gr*ns*128 + l;
  const float4* pMx   = (const float4*)mxS   + (size_t)gr*ns*256 + l;
  const float4* pM1   = (const float4*)m1S   + (size_t)gr*ns*256 + l;
  float* impP = imp + ((size_t)(gr*16 + b)*2048 + t0)*64 + 4*w;

  float4 PRA[8], GMA[2], MXA[4], M1A[4];
  float4 PRB[8], GMB[2], MXB[4], M1B[4];

  PF(A);
  for (int ts = 0; ts < ns; ts += 2) {
    STEP(A, B);
    STEP(B, A);
  }

  if (t0 + ns < 2048) {
    float* hp = hc + ((size_t)gr*64 + l)*16;
    *(float4*)(hp)      = h0;
    *(float4*)(hp + 4)  = h1;
    *(float4*)(hp + 8)  = cv0;
    *(float4*)(hp + 12) = cv1;
  } else {
    auto d4 = [](float4 a, float4 bb) {
      return fmaf(a.x, bb.x, fmaf(a.y, bb.y, fmaf(a.z, bb.z, a.w*bb.w)));
    };
    float4 wo00 = *(const float4*)(W_out + 4*w);
    float4 wo01 = *(const float4*)(W_out + 16 + 4*w);
    float4 wo10 = *(const float4*)(W_out + 32 + 4*w);
    float4 wo11 = *(const float4*)(W_out + 48 + 4*w);
    float p0 = d4(h0, wo00) + d4(h1, wo01);
    float p1 = d4(h0, wo10) + d4(h1, wo11);
    p0 += __shfl_xor(p0, 16); p0 += __shfl_xor(p0, 32);
    p1 += __shfl_xor(p1, 16); p1 += __shfl_xor(p1, 32);
    if (l < 16) {
      y[(gr*16 + l)*2 + 0] = p0 + b_out[0];
      y[(gr*16 + l)*2 + 1] = p1 + b_out[1];
    }
  }
}

extern "C" void kernel_launch(void* const* d_in, const int* in_sizes, int n_in,
                              void* d_out, int out_size, void* d_ws, size_t ws_size,
                              hipStream_t stream) {
  (void)in_sizes; (void)n_in; (void)out_size;
  const float* values  = (const float*)d_in[0];
  const float* masks   = (const float*)d_in[1];
  const float* deltas  = (const float*)d_in[2];
  const float* W_decay = (const float*)d_in[3];
  const float* b_decay = (const float*)d_in[4];
  const float* W_reg   = (const float*)d_in[5];
  const float* b_reg   = (const float*)d_in[6];
  const float* W_ih    = (const float*)d_in[7];
  const float* b_ih    = (const float*)d_in[8];
  const float* W_hh    = (const float*)d_in[9];
  const float* b_hh    = (const float*)d_in[10];
  const float* W_out   = (const float*)d_in[11];
  const float* b_out   = (const float*)d_in[12];
  float* y   = (float*)d_out;
  float* imp = (float*)d_out + 512;   // outputs: y [256,2] then imputations [256,2048,64]

  // ws: hc[64KB] | preg f32 (16*SEG*2048 + pad) | gam (16*SEG*512 + pad)
  //     | mx (16*SEG*1024 + pad) | m1 (16*SEG*1024 + pad)
  const size_t fixed = 65536 + 18432;
  size_t avail = ws_size > fixed ? ws_size - fixed : 0;
  size_t segs = avail / 294912ull;
  int SEG = (int)(segs & ~(size_t)7);
  if (SEG > 2048) SEG = 2048;
  if (SEG < 8) SEG = 8;

  float* hcW   = (float*)d_ws;
  float* pregS = (float*)((char*)d_ws + 65536);
  float* gamS  = pregS + (size_t)16*SEG*2048 + 2048;
  float* mxS   = gamS  + (size_t)16*SEG*512 + 512;
  float* m1S   = mxS   + (size_t)16*SEG*1024 + 1024;

  for (int t0 = 0; t0 < 2048; t0 += SEG) {
    int ns = 2048 - t0; if (ns > SEG) ns = SEG;
    dim3 gg(ns/8, 16);
    hipLaunchKernelGGL(g1_preg, gg, dim3(256), 0, stream,
                       values, masks, W_ih, b_ih, b_hh, pregS, mxS, m1S, t0, ns);
    hipLaunchKernelGGL(g2_gamma, gg, dim3(256), 0, stream,
                       deltas, W_decay, b_decay, gamS, t0, ns);
    hipLaunchKernelGGL(p3_rnn, dim3(16), dim3(64), 0, stream,
                       W_hh, W_reg, W_ih, b_reg, W_out, b_out,
                       pregS, gamS, mxS, m1S, hcW, y, imp, t0, ns);
  }
}

// Round 4
// 2233.826 us; speedup vs baseline: 1.1444x; 1.1083x over previous
//
#include <hip/hip_runtime.h>
#include <stdint.h>

#define L2E 1.4426950408889634f

typedef __attribute__((ext_vector_type(8))) short short8;
typedef __attribute__((ext_vector_type(4))) float floatx4;
typedef __attribute__((ext_vector_type(4))) unsigned int uintx4;
typedef __attribute__((ext_vector_type(2))) _Float16 half2v;

__device__ __forceinline__ uint32_t pkbf(float lo, float hi) {
  uint32_t r;
  asm("v_cvt_pk_bf16_f32 %0, %1, %2" : "=v"(r) : "v"(lo), "v"(hi));
  return r;
}
__device__ __forceinline__ uint32_t pkh(float lo, float hi) {
  uint32_t r;
  asm("v_cvt_pkrtz_f16_f32 %0, %1, %2" : "=v"(r) : "v"(lo), "v"(hi));
  return r;
}
__device__ __forceinline__ float2 uph(uint32_t u) {
  union { uint32_t u; half2v h; } z; z.u = u;
  return make_float2((float)z.h.x, (float)z.h.y);
}
__device__ __forceinline__ short8 mkfrag(const float* p) {
  float4 a = *(const float4*)p;
  float4 b = *(const float4*)(p + 4);
  union { uint32_t u[4]; short8 s; } z;
  z.u[0] = pkbf(a.x, a.y); z.u[1] = pkbf(a.z, a.w);
  z.u[2] = pkbf(b.x, b.y); z.u[3] = pkbf(b.z, b.w);
  return z.s;
}
__device__ __forceinline__ short8 pk8(float4 a, float4 b) {
  union { uint32_t u[4]; short8 s; } z;
  z.u[0] = pkbf(a.x, a.y); z.u[1] = pkbf(a.z, a.w);
  z.u[2] = pkbf(b.x, b.y); z.u[3] = pkbf(b.z, b.w);
  return z.s;
}
__device__ __forceinline__ short8 u4s8(uint32_t a, uint32_t b, uint32_t c, uint32_t d) {
  union { uint32_t u[4]; short8 s; } z;
  z.u[0] = a; z.u[1] = b; z.u[2] = c; z.u[3] = d;
  return z.s;
}

#define SWAP32(a, b) asm("v_permlane32_swap_b32 %0, %1" : "+v"(a), "+v"(b))
#define SWAP16(a, b) asm("v_permlane16_swap_b32 %0, %1" : "+v"(a), "+v"(b))

// ============ G1: preg (f32, slot layout) + mx/m1 (f16, slot layout) ============
// preg = W_ih[:, :64]*(m*x) + W_ih[:, 64:]*m + b_ih + b_hh
__global__ __launch_bounds__(256) void g1_pre(
    const float* __restrict__ values, const float* __restrict__ masks,
    const float* __restrict__ W_ih, const float* __restrict__ b_ih,
    const float* __restrict__ b_hh, float* __restrict__ pregS,
    float* __restrict__ mxm1S, int t0, int gstride)
{
  const int tid = threadIdx.x, wv = tid >> 6, l = tid & 63;
  const int c = l & 15, kw = l >> 4;
  const int tch = blockIdx.x, gr = blockIdx.y;
  const int tbase = t0 + tch * 32;

  short8 WF[8][4];
  #pragma unroll
  for (int tg = 0; tg < 8; ++tg)
    #pragma unroll
    for (int kc = 0; kc < 4; ++kc)
      WF[tg][kc] = mkfrag(W_ih + (size_t)(16*tg + c)*128 + 32*kc + 8*kw);

  float4 bias[8];
  #pragma unroll
  for (int tg = 0; tg < 8; ++tg) {
    float4 bi = *(const float4*)(b_ih + 16*tg + 4*kw);
    float4 bh = *(const float4*)(b_hh + 16*tg + 4*kw);
    bias[tg] = make_float4(bi.x+bh.x, bi.y+bh.y, bi.z+bh.z, bi.w+bh.w);
  }

  #pragma unroll 1
  for (int tt = 0; tt < 8; ++tt) {
    const int lt = wv*8 + tt, t_g = tbase + lt, rec = tch*32 + lt;
    const size_t ibase = ((size_t)(gr*16 + c)*2048 + t_g)*64;
    const float* xr = values + ibase;
    const float* mr = masks + ibase;
    float4 xa0 = *(const float4*)(xr + 8*kw),      xa1 = *(const float4*)(xr + 8*kw + 4);
    float4 xb0 = *(const float4*)(xr + 32 + 8*kw), xb1 = *(const float4*)(xr + 32 + 8*kw + 4);
    float4 ma0 = *(const float4*)(mr + 8*kw),      ma1 = *(const float4*)(mr + 8*kw + 4);
    float4 mb0 = *(const float4*)(mr + 32 + 8*kw), mb1 = *(const float4*)(mr + 32 + 8*kw + 4);
    float4 fa0 = make_float4(xa0.x*ma0.x, xa0.y*ma0.y, xa0.z*ma0.z, xa0.w*ma0.w);
    float4 fa1 = make_float4(xa1.x*ma1.x, xa1.y*ma1.y, xa1.z*ma1.z, xa1.w*ma1.w);
    float4 fb0 = make_float4(xb0.x*mb0.x, xb0.y*mb0.y, xb0.z*mb0.z, xb0.w*mb0.w);
    float4 fb1 = make_float4(xb1.x*mb1.x, xb1.y*mb1.y, xb1.z*mb1.z, xb1.w*mb1.w);

    short8 BF0 = pk8(fa0, fa1), BF1 = pk8(fb0, fb1);
    short8 BF2 = pk8(ma0, ma1), BF3 = pk8(mb0, mb1);

    floatx4 acc[8];
    #pragma unroll
    for (int tg = 0; tg < 8; ++tg) acc[tg] = (floatx4){0.f, 0.f, 0.f, 0.f};
    #pragma unroll
    for (int tg = 0; tg < 8; ++tg) {
      acc[tg] = __builtin_amdgcn_mfma_f32_16x16x32_bf16(WF[tg][0], BF0, acc[tg], 0, 0, 0);
      acc[tg] = __builtin_amdgcn_mfma_f32_16x16x32_bf16(WF[tg][1], BF1, acc[tg], 0, 0, 0);
      acc[tg] = __builtin_amdgcn_mfma_f32_16x16x32_bf16(WF[tg][2], BF2, acc[tg], 0, 0, 0);
      acc[tg] = __builtin_amdgcn_mfma_f32_16x16x32_bf16(WF[tg][3], BF3, acc[tg], 0, 0, 0);
    }

    uint32_t* mm = (uint32_t*)mxm1S + (size_t)(gr*gstride + rec)*1024;
    auto stw = [&](int i, int sect, float lo, float hi) {
      int tl = (i >> 4) & 1, ww = (i & 15) >> 2, jj = 2*tl + ((i >> 1) & 1);
      mm[sect*256 + (c + 16*ww)*4 + jj] = pkh(lo, hi);
    };
    stw(8*kw+0, 0, fa0.x, fa0.y); stw(8*kw+2, 0, fa0.z, fa0.w);
    stw(8*kw+4, 0, fa1.x, fa1.y); stw(8*kw+6, 0, fa1.z, fa1.w);
    stw(32+8*kw+0, 1, fb0.x, fb0.y); stw(32+8*kw+2, 1, fb0.z, fb0.w);
    stw(32+8*kw+4, 1, fb1.x, fb1.y); stw(32+8*kw+6, 1, fb1.z, fb1.w);
    stw(8*kw+0, 2, 1.f-ma0.x, 1.f-ma0.y); stw(8*kw+2, 2, 1.f-ma0.z, 1.f-ma0.w);
    stw(8*kw+4, 2, 1.f-ma1.x, 1.f-ma1.y); stw(8*kw+6, 2, 1.f-ma1.z, 1.f-ma1.w);
    stw(32+8*kw+0, 3, 1.f-mb0.x, 1.f-mb0.y); stw(32+8*kw+2, 3, 1.f-mb0.z, 1.f-mb0.w);
    stw(32+8*kw+4, 3, 1.f-mb1.x, 1.f-mb1.y); stw(32+8*kw+6, 3, 1.f-mb1.z, 1.f-mb1.w);

    float4* pf = (float4*)pregS + (size_t)(gr*gstride + rec)*512 + (c + 16*kw);
    #pragma unroll
    for (int tg = 0; tg < 8; ++tg)
      pf[tg*64] = make_float4(acc[tg][0]+bias[tg].x, acc[tg][1]+bias[tg].y,
                              acc[tg][2]+bias[tg].z, acc[tg][3]+bias[tg].w);
  }
}

// ============ G2: gamma (f16, slot layout) ============
__global__ __launch_bounds__(256) void g2_gam(
    const float* __restrict__ deltas, const float* __restrict__ W_decay,
    const float* __restrict__ b_decay, float* __restrict__ gamS,
    int t0, int gstride)
{
  const int tid = threadIdx.x, wv = tid >> 6, l = tid & 63;
  const int c = l & 15, kw = l >> 4;
  const int tch = blockIdx.x, gr = blockIdx.y;
  const int tbase = t0 + tch * 32;

  short8 AF[2][2];
  #pragma unroll
  for (int jt = 0; jt < 2; ++jt)
    #pragma unroll
    for (int kc = 0; kc < 2; ++kc)
      AF[jt][kc] = mkfrag(W_decay + (size_t)(16*jt + c)*64 + 32*kc + 8*kw);
  float4 bd0 = *(const float4*)(b_decay + 4*kw);
  float4 bd1 = *(const float4*)(b_decay + 16 + 4*kw);

  #pragma unroll 1
  for (int tt = 0; tt < 8; ++tt) {
    const int lt = wv*8 + tt, t_g = tbase + lt, rec = tch*32 + lt;
    const float* dr = deltas + ((size_t)(gr*16 + c)*2048 + t_g)*64;
    float4 da0 = *(const float4*)(dr + 8*kw),      da1 = *(const float4*)(dr + 8*kw + 4);
    float4 db0 = *(const float4*)(dr + 32 + 8*kw), db1 = *(const float4*)(dr + 32 + 8*kw + 4);
    short8 B0 = pk8(da0, da1), B1 = pk8(db0, db1);
    floatx4 zz = (floatx4){0.f, 0.f, 0.f, 0.f};
    floatx4 a0 = __builtin_amdgcn_mfma_f32_16x16x32_bf16(AF[0][0], B0, zz, 0, 0, 0);
    a0 = __builtin_amdgcn_mfma_f32_16x16x32_bf16(AF[0][1], B1, a0, 0, 0, 0);
    floatx4 a1 = __builtin_amdgcn_mfma_f32_16x16x32_bf16(AF[1][0], B0, zz, 0, 0, 0);
    a1 = __builtin_amdgcn_mfma_f32_16x16x32_bf16(AF[1][1], B1, a1, 0, 0, 0);
    float g0 = __builtin_amdgcn_exp2f(-fmaxf(a0[0]+bd0.x, 0.f) * L2E);
    float g1 = __builtin_amdgcn_exp2f(-fmaxf(a0[1]+bd0.y, 0.f) * L2E);
    float g2 = __builtin_amdgcn_exp2f(-fmaxf(a0[2]+bd0.z, 0.f) * L2E);
    float g3 = __builtin_amdgcn_exp2f(-fmaxf(a0[3]+bd0.w, 0.f) * L2E);
    float h0 = __builtin_amdgcn_exp2f(-fmaxf(a1[0]+bd1.x, 0.f) * L2E);
    float h1 = __builtin_amdgcn_exp2f(-fmaxf(a1[1]+bd1.y, 0.f) * L2E);
    float h2 = __builtin_amdgcn_exp2f(-fmaxf(a1[2]+bd1.z, 0.f) * L2E);
    float h3 = __builtin_amdgcn_exp2f(-fmaxf(a1[3]+bd1.w, 0.f) * L2E);
    uintx4 o = (uintx4){pkh(g0, g1), pkh(g2, g3), pkh(h0, h1), pkh(h2, h3)};
    ((uintx4*)gamS)[(size_t)(gr*gstride + rec)*64 + c + 16*kw] = o;
  }
}

// ============ P4: LDS-free MFMA recurrence (permlane shuffles) ============
#define PW(GI, GF, GG, GO, CC, HH) do { \
  float _si = __builtin_amdgcn_rcpf(1.f + __builtin_amdgcn_exp2f((GI) * -L2E)); \
  float _sf = __builtin_amdgcn_rcpf(1.f + __builtin_amdgcn_exp2f((GF) * -L2E)); \
  float _so = __builtin_amdgcn_rcpf(1.f + __builtin_amdgcn_exp2f((GO) * -L2E)); \
  float _tg = 1.f - 2.f*__builtin_amdgcn_rcpf(1.f + __builtin_amdgcn_exp2f((GG) * (2.f*L2E))); \
  float _cn = fmaf(_sf, (CC), _si*_tg); \
  float _tc = 1.f - 2.f*__builtin_amdgcn_rcpf(1.f + __builtin_amdgcn_exp2f(_cn * (2.f*L2E))); \
  (CC) = _cn; (HH) = _so * _tc; \
} while (0)

__global__ __launch_bounds__(64, 1) void p4_rnn(
    const float* __restrict__ W_hh, const float* __restrict__ W_reg,
    const float* __restrict__ W_ih, const float* __restrict__ b_reg,
    const float* __restrict__ W_out, const float* __restrict__ b_out,
    const float* __restrict__ pregS, const float* __restrict__ gamS,
    const float* __restrict__ mxm1S,
    float* __restrict__ hc, float* __restrict__ y, float* __restrict__ imp,
    int t0, int ns, int gstride)
{
  const int l = threadIdx.x, gr = blockIdx.x;
  const int b = l & 15, w = l >> 4;

  short8 WhhA[8], WxcA0[8], WxcA1[8], WregA[4];
  #pragma unroll
  for (int t = 0; t < 8; ++t) {
    WhhA[t]  = mkfrag(W_hh + (size_t)(16*t + b)*32 + 8*w);
    WxcA0[t] = mkfrag(W_ih + (size_t)(16*t + b)*128 + 8*w);
    WxcA1[t] = mkfrag(W_ih + (size_t)(16*t + b)*128 + 32 + 8*w);
  }
  #pragma unroll
  for (int t = 0; t < 4; ++t) WregA[t] = mkfrag(W_reg + (size_t)(16*t + b)*32 + 8*w);
  floatx4 brC[4];
  #pragma unroll
  for (int t = 0; t < 4; ++t) {
    float4 v = *(const float4*)(b_reg + 16*t + 4*w);
    brC[t] = (floatx4){v.x, v.y, v.z, v.w};
  }

  float4 h0, h1, cv0, cv1;
  if (t0 == 0) {
    h0 = h1 = cv0 = cv1 = make_float4(0.f, 0.f, 0.f, 0.f);
  } else {
    const float* hp = hc + ((size_t)gr*64 + l)*16;
    h0  = *(const float4*)(hp);
    h1  = *(const float4*)(hp + 4);
    cv0 = *(const float4*)(hp + 8);
    cv1 = *(const float4*)(hp + 12);
  }

  const floatx4* pPreg = (const floatx4*)pregS + (size_t)gr*gstride*512;
  const uintx4*  pGam  = (const uintx4*)gamS  + (size_t)gr*gstride*64;
  const uintx4*  pMM   = (const uintx4*)mxm1S + (size_t)gr*gstride*256;
  float* impP = imp + ((size_t)(gr*16 + b)*2048 + t0)*64 + 4*w;

  floatx4 rPR[4][8];
  uintx4 rGM[4], rMX[4][2], rM1[4][2];

  auto PREF = [&](int s, int j) {
    #pragma unroll
    for (int t = 0; t < 8; ++t) rPR[j][t] = pPreg[(size_t)s*512 + t*64 + l];
    rGM[j]    = pGam[(size_t)s*64 + l];
    rMX[j][0] = pMM[(size_t)s*256 + l];
    rMX[j][1] = pMM[(size_t)s*256 + 64 + l];
    rM1[j][0] = pMM[(size_t)s*256 + 128 + l];
    rM1[j][1] = pMM[(size_t)s*256 + 192 + l];
  };

  auto BODY = [&](int j) {
    float2 gA = uph(rGM[j][0]), gB = uph(rGM[j][1]);
    float2 gC = uph(rGM[j][2]), gD = uph(rGM[j][3]);
    float4 hd0 = make_float4(h0.x*gA.x, h0.y*gA.y, h0.z*gB.x, h0.w*gB.y);
    float4 hd1 = make_float4(h1.x*gC.x, h1.y*gC.y, h1.z*gD.x, h1.w*gD.y);
    uint32_t P0 = pkbf(hd0.x, hd0.y), P1 = pkbf(hd0.z, hd0.w);
    uint32_t Q0 = pkbf(hd1.x, hd1.y), Q1 = pkbf(hd1.z, hd1.w);
    SWAP32(P0, Q0); SWAP32(P1, Q1);
    SWAP16(P0, Q0); SWAP16(P1, Q1);
    short8 Bhd = u4s8(P0, P1, Q0, Q1);

    floatx4 uu[4];
    #pragma unroll
    for (int t = 0; t < 4; ++t)
      uu[t] = __builtin_amdgcn_mfma_f32_16x16x32_bf16(WregA[t], Bhd, brC[t], 0, 0, 0);
    floatx4 ga[8];
    #pragma unroll
    for (int t = 0; t < 8; ++t)
      ga[t] = __builtin_amdgcn_mfma_f32_16x16x32_bf16(WhhA[t], Bhd, rPR[j][t], 0, 0, 0);

    uint32_t U[8];
    #pragma unroll
    for (int t = 0; t < 4; ++t) {
      float2 m1a = uph(rM1[j][t>>1][2*(t&1)]), m1b = uph(rM1[j][t>>1][2*(t&1)+1]);
      float2 mxa = uph(rMX[j][t>>1][2*(t&1)]), mxb = uph(rMX[j][t>>1][2*(t&1)+1]);
      float v0 = m1a.x*uu[t][0], v1 = m1a.y*uu[t][1];
      float v2 = m1b.x*uu[t][2], v3 = m1b.y*uu[t][3];
      *(float4*)(impP + 16*t) = make_float4(v0+mxa.x, v1+mxa.y, v2+mxb.x, v3+mxb.y);
      U[2*t]   = pkbf(v0, v1);
      U[2*t+1] = pkbf(v2, v3);
    }
    SWAP32(U[0], U[2]); SWAP32(U[1], U[3]);
    SWAP16(U[0], U[2]); SWAP16(U[1], U[3]);
    short8 Bv0 = u4s8(U[0], U[1], U[2], U[3]);
    SWAP32(U[4], U[6]); SWAP32(U[5], U[7]);
    SWAP16(U[4], U[6]); SWAP16(U[5], U[7]);
    short8 Bv1 = u4s8(U[4], U[5], U[6], U[7]);

    #pragma unroll
    for (int t = 0; t < 8; ++t)
      ga[t] = __builtin_amdgcn_mfma_f32_16x16x32_bf16(WxcA0[t], Bv0, ga[t], 0, 0, 0);
    #pragma unroll
    for (int t = 0; t < 8; ++t)
      ga[t] = __builtin_amdgcn_mfma_f32_16x16x32_bf16(WxcA1[t], Bv1, ga[t], 0, 0, 0);
    impP += 64;

    PW(ga[0][0], ga[2][0], ga[4][0], ga[6][0], cv0.x, h0.x);
    PW(ga[0][1], ga[2][1], ga[4][1], ga[6][1], cv0.y, h0.y);
    PW(ga[0][2], ga[2][2], ga[4][2], ga[6][2], cv0.z, h0.z);
    PW(ga[0][3], ga[2][3], ga[4][3], ga[6][3], cv0.w, h0.w);
    PW(ga[1][0], ga[3][0], ga[5][0], ga[7][0], cv1.x, h1.x);
    PW(ga[1][1], ga[3][1], ga[5][1], ga[7][1], cv1.y, h1.y);
    PW(ga[1][2], ga[3][2], ga[5][2], ga[7][2], cv1.z, h1.z);
    PW(ga[1][3], ga[3][3], ga[5][3], ga[7][3], cv1.w, h1.w);
  };

  PREF(0, 0); PREF(1, 1); PREF(2, 2); PREF(3, 3);
  #pragma unroll 1
  for (int sb = 0; sb < ns; sb += 4) {
    BODY(0); PREF(sb + 4, 0);
    BODY(1); PREF(sb + 5, 1);
    BODY(2); PREF(sb + 6, 2);
    BODY(3); PREF(sb + 7, 3);
  }

  if (t0 + ns < 2048) {
    float* hp = hc + ((size_t)gr*64 + l)*16;
    *(float4*)(hp)      = h0;
    *(float4*)(hp + 4)  = h1;
    *(float4*)(hp + 8)  = cv0;
    *(float4*)(hp + 12) = cv1;
  } else {
    auto d4 = [](float4 a, float4 bb) {
      return fmaf(a.x, bb.x, fmaf(a.y, bb.y, fmaf(a.z, bb.z, a.w*bb.w)));
    };
    float4 wo00 = *(const float4*)(W_out + 4*w);
    float4 wo01 = *(const float4*)(W_out + 16 + 4*w);
    float4 wo10 = *(const float4*)(W_out + 32 + 4*w);
    float4 wo11 = *(const float4*)(W_out + 48 + 4*w);
    float p0 = d4(h0, wo00) + d4(h1, wo01);
    float p1 = d4(h0, wo10) + d4(h1, wo11);
    p0 += __shfl_xor(p0, 16); p0 += __shfl_xor(p0, 32);
    p1 += __shfl_xor(p1, 16); p1 += __shfl_xor(p1, 32);
    if (l < 16) {
      y[(gr*16 + l)*2 + 0] = p0 + b_out[0];
      y[(gr*16 + l)*2 + 1] = p1 + b_out[1];
    }
  }
}

extern "C" void kernel_launch(void* const* d_in, const int* in_sizes, int n_in,
                              void* d_out, int out_size, void* d_ws, size_t ws_size,
                              hipStream_t stream) {
  (void)in_sizes; (void)n_in; (void)out_size;
  const float* values  = (const float*)d_in[0];
  const float* masks   = (const float*)d_in[1];
  const float* deltas  = (const float*)d_in[2];
  const float* W_decay = (const float*)d_in[3];
  const float* b_decay = (const float*)d_in[4];
  const float* W_reg   = (const float*)d_in[5];
  const float* b_reg   = (const float*)d_in[6];
  const float* W_ih    = (const float*)d_in[7];
  const float* b_ih    = (const float*)d_in[8];
  const float* W_hh    = (const float*)d_in[9];
  const float* b_hh    = (const float*)d_in[10];
  const float* W_out   = (const float*)d_in[11];
  const float* b_out   = (const float*)d_in[12];
  float* y   = (float*)d_out;
  float* imp = (float*)d_out + 512;   // outputs: y [256,2] then imputations [256,2048,64]

  // ws: hc[64KB] | preg f32 (16*gstride*2048 fl) | gam f16 (16*gstride*256 fl) | mxm1 f16 (16*gstride*1024 fl)
  int SEG = 2048;
  while (SEG > 32) {
    size_t need = 65536ull + 16ull*(size_t)(SEG + 8)*13312ull;
    if (need <= ws_size) break;
    SEG >>= 1;
  }
  const int gstride = SEG + 8;

  float* hcW   = (float*)d_ws;
  float* pregS = (float*)((char*)d_ws + 65536);
  float* gamS  = pregS + (size_t)16*gstride*2048;
  float* mxm1S = gamS  + (size_t)16*gstride*256;

  for (int t0 = 0; t0 < 2048; t0 += SEG) {
    dim3 gg(SEG/32, 16);
    hipLaunchKernelGGL(g1_pre, gg, dim3(256), 0, stream,
                       values, masks, W_ih, b_ih, b_hh, pregS, mxm1S, t0, gstride);
    hipLaunchKernelGGL(g2_gam, gg, dim3(256), 0, stream,
                       deltas, W_decay, b_decay, gamS, t0, gstride);
    hipLaunchKernelGGL(p4_rnn, dim3(16), dim3(64), 0, stream,
                       W_hh, W_reg, W_ih, b_reg, W_out, b_out,
                       pregS, gamS, mxm1S, hcW, y, imp, t0, SEG, gstride);
  }
}